// Round 1
// baseline (532.956 us; speedup 1.0000x reference)
//
#include <hip/hip_runtime.h>

#define IN_DIM 32
#define OUT_DIM 64

#define BUCKET_SHIFT 7                      // 128 nodes per bucket
#define BUCKET_NODES (1 << BUCKET_SHIFT)    // 128
#define CAP 2688                            // per-bucket edge capacity (mean 2048, sigma ~45 -> +14 sigma)
#define CURSOR_STRIDE 16                    // one cursor per 64B line: avoids same-line atomic serialization

// Kernel 1: one-pass counting-bucket sort of edges.
// Per edge: ONE int atomic (vs 32 float atomics before) + one packed u32 write.
// pack = (src << 7) | (dst & 127); src < 2^17 so this fits in 24 bits.
__global__ __launch_bounds__(256) void bucket_scatter(
    const int* __restrict__ src,
    const int* __restrict__ dst,
    int* __restrict__ cursors,
    unsigned int* __restrict__ bdata,
    int n_edges) {
    int e = blockIdx.x * 256 + threadIdx.x;
    if (e >= n_edges) return;
    int s = src[e];
    int t = dst[e];
    int b = t >> BUCKET_SHIFT;
    int pos = atomicAdd(&cursors[b * CURSOR_STRIDE], 1);
    if (pos < CAP) {  // defensive clamp; statistically unreachable for this input
        bdata[(long long)b * CAP + pos] =
            ((unsigned int)s << BUCKET_SHIFT) | (unsigned int)(t & (BUCKET_NODES - 1));
    }
}

// Kernel 2: per-bucket accumulate in LDS + fused projection. `h` never hits HBM.
// Block = 256 threads = 8 edge-groups of 32 lanes (lane = in-dim).
// tile[local][d]: bank = d -> conflict-free LDS atomics (2 lanes/bank per wave = free).
__global__ __launch_bounds__(256) void bucket_gather_project(
    const float* __restrict__ feature,
    const unsigned int* __restrict__ bdata,
    const int* __restrict__ cursors,
    const float* __restrict__ W,
    const float* __restrict__ bias_v,
    float* __restrict__ out,
    int n_nodes) {
    __shared__ float tile[BUCKET_NODES][IN_DIM];  // 16 KB
    __shared__ float Ws[IN_DIM * OUT_DIM];        // 8 KB
    int tx = threadIdx.x;
    int bk = blockIdx.x;

    for (int i = tx; i < BUCKET_NODES * IN_DIM; i += 256)
        (&tile[0][0])[i] = 0.0f;
    for (int i = tx; i < IN_DIM * OUT_DIM; i += 256)
        Ws[i] = W[i];
    __syncthreads();

    int cnt = cursors[bk * CURSOR_STRIDE];
    if (cnt > CAP) cnt = CAP;
    const unsigned int* bd = bdata + (long long)bk * CAP;

    int g = tx >> 5;  // edge-group 0..7
    int d = tx & 31;  // in-dim

    int e = g;
    // unroll-4: 4 gathers in flight per thread before the LDS atomics.
    for (; e + 24 < cnt; e += 32) {
        unsigned int p0 = bd[e];
        unsigned int p1 = bd[e + 8];
        unsigned int p2 = bd[e + 16];
        unsigned int p3 = bd[e + 24];
        float v0 = feature[(long long)(p0 >> BUCKET_SHIFT) * IN_DIM + d];
        float v1 = feature[(long long)(p1 >> BUCKET_SHIFT) * IN_DIM + d];
        float v2 = feature[(long long)(p2 >> BUCKET_SHIFT) * IN_DIM + d];
        float v3 = feature[(long long)(p3 >> BUCKET_SHIFT) * IN_DIM + d];
        atomicAdd(&tile[p0 & (BUCKET_NODES - 1)][d], v0);
        atomicAdd(&tile[p1 & (BUCKET_NODES - 1)][d], v1);
        atomicAdd(&tile[p2 & (BUCKET_NODES - 1)][d], v2);
        atomicAdd(&tile[p3 & (BUCKET_NODES - 1)][d], v3);
    }
    for (; e < cnt; e += 8) {
        unsigned int p = bd[e];
        float v = feature[(long long)(p >> BUCKET_SHIFT) * IN_DIM + d];
        atomicAdd(&tile[p & (BUCKET_NODES - 1)][d], v);
    }
    __syncthreads();

    // Fused projection: out[node][col] = sum_k tile[r][k] * W[k][col] + b[col]
    // 256 threads = 4 rows x 64 cols per iteration; r uniform per wave.
    int col = tx & 63;
    int r0 = tx >> 6;  // 0..3
    int node_base = bk << BUCKET_SHIFT;
    float acc_bias = bias_v[col];
    for (int r = r0; r < BUCKET_NODES; r += 4) {
        int node = node_base + r;
        if (node >= n_nodes) break;  // r is wave-uniform; no sync below
        float acc = acc_bias;
#pragma unroll
        for (int k = 0; k < IN_DIM; ++k)
            acc += tile[r][k] * Ws[k * OUT_DIM + col];  // tile: broadcast; Ws: 2 lanes/bank (free)
        out[(long long)node * OUT_DIM + col] = acc;
    }
}

extern "C" void kernel_launch(void* const* d_in, const int* in_sizes, int n_in,
                              void* d_out, int out_size, void* d_ws, size_t ws_size,
                              hipStream_t stream) {
    const float* feature = (const float*)d_in[0];
    const int* src = (const int*)d_in[1];
    const int* dst = (const int*)d_in[2];
    const float* W = (const float*)d_in[3];
    const float* b = (const float*)d_in[4];
    float* out = (float*)d_out;

    int n_nodes = in_sizes[0] / IN_DIM;  // 100000
    int n_edges = in_sizes[1];           // 1600000
    int n_buckets = (n_nodes + BUCKET_NODES - 1) >> BUCKET_SHIFT;  // 782

    // Workspace layout: [cursors: n_buckets*64B][bdata: n_buckets*CAP*4B] ~ 8.45 MB total
    int* cursors = (int*)d_ws;
    unsigned int* bdata =
        (unsigned int*)((char*)d_ws + (size_t)n_buckets * CURSOR_STRIDE * sizeof(int));

    // Workspace is re-poisoned to 0xAA before every launch — zero only the cursors (50 KB).
    hipMemsetAsync(cursors, 0, (size_t)n_buckets * CURSOR_STRIDE * sizeof(int), stream);

    int blocks = (n_edges + 255) / 256;
    bucket_scatter<<<blocks, 256, 0, stream>>>(src, dst, cursors, bdata, n_edges);

    bucket_gather_project<<<n_buckets, 256, 0, stream>>>(feature, bdata, cursors, W, b, out,
                                                         n_nodes);
}

// Round 2
// 353.428 us; speedup vs baseline: 1.5080x; 1.5080x over previous
//
#include <hip/hip_runtime.h>

#define IN_DIM 32
#define OUT_DIM 64
#define N_PAD 100352  // 100000 rounded up to 1024

// ---------------------------------------------------------------------------
// CSR build, exact (no capacity gamble):
//   1. hist:   counts[dst]++            (1.6M atomics, ~16 per address -> no contention)
//   2. scan1:  per-1024-block exclusive scan of counts -> offs, block sums
//   3. scan2:  scan the 98 block sums (single small block)
//   4. scan3:  offs[i] += top[i>>10];  cursor[i] = offs[i]
//   5. scatter: bdata[atomicAdd(&cursor[dst],1)] = src
//   6. gather_proj: one 32-lane group per node: acc[d] = sum feature[src][d],
//      then fused projection out = acc @ W + b.  h never exists in HBM.
// ---------------------------------------------------------------------------

__global__ __launch_bounds__(256) void csr_hist(
    const int* __restrict__ dst, int* __restrict__ counts, int n_edges) {
    int e = blockIdx.x * 256 + threadIdx.x;
    if (e < n_edges) atomicAdd(&counts[dst[e]], 1);
}

// 256 threads scan 1024 elements (4 per thread).
__global__ __launch_bounds__(256) void csr_scan1(
    const int* __restrict__ counts, int* __restrict__ offs,
    int* __restrict__ bsum, int n) {
    __shared__ int lsum[256];
    int t = threadIdx.x;
    int base = blockIdx.x * 1024 + t * 4;
    int c0 = (base + 0 < n) ? counts[base + 0] : 0;
    int c1 = (base + 1 < n) ? counts[base + 1] : 0;
    int c2 = (base + 2 < n) ? counts[base + 2] : 0;
    int c3 = (base + 3 < n) ? counts[base + 3] : 0;
    int s = c0 + c1 + c2 + c3;
    lsum[t] = s;
    __syncthreads();
    // Hillis-Steele inclusive scan (read, sync, add, sync avoids the race)
    for (int off = 1; off < 256; off <<= 1) {
        int v = (t >= off) ? lsum[t - off] : 0;
        __syncthreads();
        lsum[t] += v;
        __syncthreads();
    }
    int run = lsum[t] - s;  // exclusive prefix of this thread's chunk
    if (base + 0 < n) offs[base + 0] = run;
    run += c0;
    if (base + 1 < n) offs[base + 1] = run;
    run += c1;
    if (base + 2 < n) offs[base + 2] = run;
    run += c2;
    if (base + 3 < n) offs[base + 3] = run;
    if (t == 255) bsum[blockIdx.x] = lsum[255];
}

// Single block scans nb (<=128) block sums -> exclusive tops.
__global__ __launch_bounds__(128) void csr_scan2(
    const int* __restrict__ bsum, int* __restrict__ top, int nb) {
    __shared__ int ls[128];
    int t = threadIdx.x;
    int v0 = (t < nb) ? bsum[t] : 0;
    ls[t] = v0;
    __syncthreads();
    for (int off = 1; off < 128; off <<= 1) {
        int v = (t >= off) ? ls[t - off] : 0;
        __syncthreads();
        ls[t] += v;
        __syncthreads();
    }
    if (t < nb) top[t] = ls[t] - v0;  // exclusive
}

__global__ __launch_bounds__(256) void csr_scan3(
    int* __restrict__ offs, int* __restrict__ cursor,
    const int* __restrict__ top, int n) {
    int i = blockIdx.x * 256 + threadIdx.x;
    if (i < n) {
        int o = offs[i] + top[i >> 10];
        offs[i] = o;
        cursor[i] = o;
    }
}

__global__ __launch_bounds__(256) void csr_scatter(
    const int* __restrict__ src, const int* __restrict__ dst,
    int* __restrict__ cursor, int* __restrict__ bdata, int n_edges) {
    int e = blockIdx.x * 256 + threadIdx.x;
    if (e >= n_edges) return;
    int s = src[e];
    int pos = atomicAdd(&cursor[dst[e]], 1);
    bdata[pos] = s;
}

// Block = 1024 threads = 32 groups of 32 lanes; group g owns node base+g.
// Gather: acc[d] = sum over CSR segment of feature[src][d]  (register accum,
// no atomics). Then fused projection via LDS (Ws: 2 lanes/bank = free).
__global__ __launch_bounds__(1024) void csr_gather_proj(
    const float* __restrict__ feature,
    const int* __restrict__ offs,
    const int* __restrict__ cursor,   // after scatter: cursor[n] == segment end
    const int* __restrict__ bdata,
    const float* __restrict__ W,
    const float* __restrict__ bias_v,
    float* __restrict__ out,
    int n_nodes) {
    __shared__ float Ws[IN_DIM * OUT_DIM];  // 8 KB
    __shared__ float hs[32][IN_DIM];        // 4 KB
    int tx = threadIdx.x;
    for (int i = tx; i < IN_DIM * OUT_DIM; i += 1024) Ws[i] = W[i];

    int g = tx >> 5;  // 0..31: node group
    int d = tx & 31;  // in-dim lane
    int node = blockIdx.x * 32 + g;

    float acc = 0.0f;
    if (node < n_nodes) {
        int j = offs[node];
        int end = cursor[node];
        // unroll-2: two bdata broadcasts + two coalesced 128B feature rows in flight
        for (; j + 1 < end; j += 2) {
            int sa = bdata[j];
            int sb = bdata[j + 1];
            acc += feature[sa * IN_DIM + d];
            acc += feature[sb * IN_DIM + d];
        }
        if (j < end) acc += feature[bdata[j] * IN_DIM + d];
    }
    hs[g][d] = acc;
    __syncthreads();

    // Projection: 1024 threads = 16 rows x 64 cols; 32 rows -> 2 passes.
    int col = tx & 63;
    int r0 = tx >> 6;  // 0..15
    float bb = bias_v[col];
    for (int r = r0; r < 32; r += 16) {
        int n2 = blockIdx.x * 32 + r;
        if (n2 < n_nodes) {
            float a = bb;
#pragma unroll
            for (int k = 0; k < IN_DIM; ++k)
                a += hs[r][k] * Ws[k * OUT_DIM + col];  // hs: broadcast; Ws: free
            out[n2 * OUT_DIM + col] = a;
        }
    }
}

extern "C" void kernel_launch(void* const* d_in, const int* in_sizes, int n_in,
                              void* d_out, int out_size, void* d_ws, size_t ws_size,
                              hipStream_t stream) {
    const float* feature = (const float*)d_in[0];
    const int* src = (const int*)d_in[1];
    const int* dst = (const int*)d_in[2];
    const float* W = (const float*)d_in[3];
    const float* b = (const float*)d_in[4];
    float* out = (float*)d_out;

    int n_nodes = in_sizes[0] / IN_DIM;  // 100000
    int n_edges = in_sizes[1];           // 1600000

    // Workspace layout (~7.7 MB):
    int* counts = (int*)d_ws;            // N_PAD
    int* offs = counts + N_PAD;          // N_PAD
    int* cursor = offs + N_PAD;          // N_PAD
    int* bsum = cursor + N_PAD;          // 128
    int* top = bsum + 128;               // 128
    int* bdata = top + 128;              // n_edges

    // Workspace is re-poisoned before every launch — zero only counts (400 KB).
    hipMemsetAsync(counts, 0, (size_t)n_nodes * sizeof(int), stream);

    int eblocks = (n_edges + 255) / 256;
    csr_hist<<<eblocks, 256, 0, stream>>>(dst, counts, n_edges);

    int sblocks = (n_nodes + 1023) / 1024;  // 98
    csr_scan1<<<sblocks, 256, 0, stream>>>(counts, offs, bsum, n_nodes);
    csr_scan2<<<1, 128, 0, stream>>>(bsum, top, sblocks);
    csr_scan3<<<(n_nodes + 255) / 256, 256, 0, stream>>>(offs, cursor, top, n_nodes);

    csr_scatter<<<eblocks, 256, 0, stream>>>(src, dst, cursor, bdata, n_edges);

    int gblocks = (n_nodes + 31) / 32;  // 3125
    csr_gather_proj<<<gblocks, 1024, 0, stream>>>(feature, offs, cursor, bdata, W, b, out,
                                                  n_nodes);
}